// Round 2
// baseline (695.305 us; speedup 1.0000x reference)
//
#include <hip/hip_runtime.h>

#define HD 64
#define NNODE 50000
#define NEDGE 100000
#define NGR 500
#define NPG 100      // nodes per graph (sorted, contiguous, equal size)
#define EPAD 100352  // 392 blocks * 256 edges

typedef _Float16 f16;
typedef _Float16 f16x4 __attribute__((ext_vector_type(4)));
typedef _Float16 f16x8 __attribute__((ext_vector_type(8)));
typedef float f32x4 __attribute__((ext_vector_type(4)));

__device__ __forceinline__ float sigmoidf_(float x) { return 1.f / (1.f + __expf(-x)); }

// ---------------- K1: h = relu(nfeat @ lin0_w + b), [N,32]@[32,64] ----------------
__global__ void k_node_init(const float* __restrict__ nfeat, const float* __restrict__ w,
                            const float* __restrict__ b, float* __restrict__ h) {
    int idx = blockIdx.x * 256 + threadIdx.x;
    int n = idx >> 6, o = idx & 63;
    if (n >= NNODE) return;
    const float* nf = nfeat + n * 32;
    float acc = b[o];
#pragma unroll
    for (int i = 0; i < 32; i++) acc += nf[i] * w[i * 64 + o];
    h[idx] = fmaxf(acc, 0.f);
}

// ---------------- K2: u[e][0:128]=f16(relu(efeat@ew1+eb1)), u[e][128]=1, rest 0 ----
__global__ void k_edge_mlp(const float* __restrict__ efeat, const float* __restrict__ w,
                           const float* __restrict__ b, f16* __restrict__ u) {
    int idx = blockIdx.x * 256 + threadIdx.x;
    if (idx >= EPAD * 136) return;
    int e = idx / 136, k = idx - e * 136;
    f16 val = (f16)0.f;
    if (e < NEDGE) {
        if (k < 128) {
            const float* ef = efeat + e * 5;
            float acc = b[k];
#pragma unroll
            for (int i = 0; i < 5; i++) acc += ef[i] * w[i * 128 + k];
            val = (f16)fmaxf(acc, 0.f);
        } else if (k == 128) {
            val = (f16)1.f;
        }
    }
    u[idx] = val;
}

// ---------------- K3: pack W2ext (= [ew2; eb2; zeros], [8448][64]) into MFMA B-fragment order
// w2hp[s][j][lane][q] = W2ext[s*32 + (lane>>4)*8 + q][j*16 + (lane&15)]
__global__ void k_pack_b(const float* __restrict__ ew2, const float* __restrict__ eb2,
                         f16* __restrict__ w2hp) {
    int idx = blockIdx.x * 256 + threadIdx.x;
    if (idx >= 540672) return;  // 264*4*64*8
    int q = idx & 7, l = (idx >> 3) & 63, j = (idx >> 9) & 3, s = idx >> 11;
    int k = s * 32 + (l >> 4) * 8 + q;
    int n = j * 16 + (l & 15);
    float v = 0.f;
    if (k < 8192) v = ew2[k * 64 + n];          // ew2 flat == W2flat[k][n]
    else if (k < 8256) v = eb2[(k - 8192) * 64 + n];
    w2hp[idx] = (f16)v;
}

// ---------------- K3b: GRU weights -> f16 ----------------
__global__ void k_prep_gru(const float* __restrict__ wih, const float* __restrict__ whh,
                           f16* __restrict__ wih16, f16* __restrict__ whh16) {
    int idx = blockIdx.x * 256 + threadIdx.x;
    if (idx >= 12288) return;
    wih16[idx] = (f16)wih[idx];
    whh16[idx] = (f16)whh[idx];
}

// ---------------- K3c: generic small f32 transpose (LSTM weights) ----------------
__global__ void k_transpose_f32(const float* __restrict__ in, float* __restrict__ outp,
                                int rows, int cols) {
    int idx = blockIdx.x * 256 + threadIdx.x;
    if (idx >= rows * cols) return;
    int r = idx / cols, c = idx - r * cols;
    outp[c * rows + r] = in[idx];
}

// ---------------- degree ----------------
__global__ void k_deg_count(const int* __restrict__ dst, int* __restrict__ cnt) {
    int e = blockIdx.x * 256 + threadIdx.x;
    if (e < NEDGE) atomicAdd(&cnt[dst[e]], 1);
}
__global__ void k_deg_inv(const int* __restrict__ cnt, float* __restrict__ dinv) {
    int n = blockIdx.x * 256 + threadIdx.x;
    if (n < NNODE) dinv[n] = 1.f / (float)max(cnt[n], 1);
}

// ---------------- K6: fused msg + scatter ----------------
// msg[e,0:64] = sum_k A[e,k] * W2ext[k,:], A[e, ku*64+h] = u[e,ku]*x[e,h], K=8448 (33 chunks x 8 ksteps x 32)
// Block: 256 thr = 4 waves, each wave 64 edges (M-rep 4). B double-buffered in LDS (2x32KB).
__global__ __launch_bounds__(256, 2) void k_msg_fused(
    const float* __restrict__ h, const f16* __restrict__ u, const f16* __restrict__ w2hp,
    const int* __restrict__ src, const int* __restrict__ dst, float* __restrict__ agg) {
    __shared__ __attribute__((aligned(16))) f16 sB[32768];  // 2 bufs x 2048 f16x8
    __shared__ int sdst[256];
    int t = threadIdx.x;
    int w = t >> 6, l = t & 63;
    int lr = l & 15, lg = l >> 4;
    int m0 = blockIdx.x * 256;
    {
        int e = m0 + t;
        sdst[t] = (e < NEDGE) ? dst[e] : -1;
    }
    int row[4];
#pragma unroll
    for (int i = 0; i < 4; i++) row[i] = m0 + w * 64 + i * 16 + lr;
    // x fragments: xf[i][p][q] = f16(h[src[row_i]][p*32 + lg*8 + q])
    f16x8 xf[4][2];
#pragma unroll
    for (int i = 0; i < 4; i++) {
        int e = row[i] < NEDGE ? row[i] : 0;
        const float* xb = h + (size_t)src[e] * 64;
#pragma unroll
        for (int p = 0; p < 2; p++) {
            float4 v0 = *(const float4*)(xb + p * 32 + lg * 8);
            float4 v1 = *(const float4*)(xb + p * 32 + lg * 8 + 4);
            f16x8 xv;
            xv[0] = (f16)v0.x; xv[1] = (f16)v0.y; xv[2] = (f16)v0.z; xv[3] = (f16)v0.w;
            xv[4] = (f16)v1.x; xv[5] = (f16)v1.y; xv[6] = (f16)v1.z; xv[7] = (f16)v1.w;
            xf[i][p] = xv;
        }
    }
    const f16x8* gB = (const f16x8*)w2hp;
    f16x8* sB8 = (f16x8*)sB;
    f16x8 stg[8];
    f16x4 ucur[4], unext[4];
#pragma unroll
    for (int ph = 0; ph < 8; ph++) stg[ph] = gB[ph * 256 + t];
#pragma unroll
    for (int i = 0; i < 4; i++) ucur[i] = *(const f16x4*)(u + (size_t)row[i] * 136);
#pragma unroll
    for (int ph = 0; ph < 8; ph++) sB8[ph * 256 + t] = stg[ph];
    __syncthreads();
    f32x4 acc[4][4];
#pragma unroll
    for (int i = 0; i < 4; i++)
#pragma unroll
        for (int j = 0; j < 4; j++) acc[i][j] = (f32x4){0.f, 0.f, 0.f, 0.f};
    for (int c = 0; c < 33; c++) {
        int b = c & 1;
        if (c < 32) {  // T14: issue next-chunk loads early
#pragma unroll
            for (int ph = 0; ph < 8; ph++) stg[ph] = gB[(c + 1) * 2048 + ph * 256 + t];
#pragma unroll
            for (int i = 0; i < 4; i++)
                unext[i] = *(const f16x4*)(u + (size_t)row[i] * 136 + (c + 1) * 4);
        }
        const f16x8* bb = sB8 + b * 2048;
#pragma unroll
        for (int sl = 0; sl < 8; sl++) {
            f16x8 bfr[4];
#pragma unroll
            for (int j = 0; j < 4; j++) bfr[j] = bb[(sl * 4 + j) * 64 + l];
#pragma unroll
            for (int i = 0; i < 4; i++) {
                f16x8 av = xf[i][sl & 1] * ucur[i][sl >> 1];  // a-frag: u[ku]*x[h], k = s*32+lg*8+q
#pragma unroll
                for (int j = 0; j < 4; j++)
                    acc[i][j] = __builtin_amdgcn_mfma_f32_16x16x32_f16(av, bfr[j], acc[i][j], 0, 0, 0);
            }
        }
        if (c < 32) {  // write-late into the other buffer
            f16x8* sw = sB8 + (b ^ 1) * 2048;
#pragma unroll
            for (int ph = 0; ph < 8; ph++) sw[ph * 256 + t] = stg[ph];
#pragma unroll
            for (int i = 0; i < 4; i++) ucur[i] = unext[i];
        }
        __syncthreads();
    }
    // scatter: C layout col=lane&15, row=(lane>>4)*4+reg
#pragma unroll
    for (int i = 0; i < 4; i++) {
#pragma unroll
        for (int r = 0; r < 4; r++) {
            int d = sdst[w * 64 + i * 16 + lg * 4 + r];
            if (d >= 0) {
                float* ap = agg + (size_t)d * 64 + lr;
#pragma unroll
                for (int j = 0; j < 4; j++) atomicAdd(ap + j * 16, acc[i][j][r]);
            }
        }
    }
}

// ---------------- K7: GRU update, 8 nodes/block, f16 weights staged in LDS ----------------
#define WP 72  // padded LDS row stride in f16 (144B, 16B aligned)
__global__ __launch_bounds__(256) void k_gru(const float* __restrict__ agg,
                                             const float* __restrict__ dinv,
                                             const float* __restrict__ convb,
                                             const f16* __restrict__ wih16,
                                             const f16* __restrict__ whh16,
                                             const float* __restrict__ bih,
                                             const float* __restrict__ bhh,
                                             float* __restrict__ h) {
    __shared__ f16 sWih[192 * WP];
    __shared__ f16 sWhh[192 * WP];
    __shared__ f16 sm[8 * 64];
    __shared__ f16 sh16[8 * 64];
    __shared__ float sh32[8][64];
    __shared__ float sgi[8 * 192];
    __shared__ float sgh[8 * 192];
    int t = threadIdx.x;
    int nb = blockIdx.x * 8;
    const f16x8* wih8 = (const f16x8*)wih16;
    const f16x8* whh8 = (const f16x8*)whh16;
    for (int idx = t; idx < 1536; idx += 256) {
        int j = idx >> 3, k8 = idx & 7;
        *(f16x8*)(sWih + j * WP + k8 * 8) = wih8[idx];
        *(f16x8*)(sWhh + j * WP + k8 * 8) = whh8[idx];
    }
#pragma unroll
    for (int ii = 0; ii < 2; ii++) {
        int idx = t + 256 * ii;
        int i = idx >> 6, k = idx & 63;
        int node = nb + i;
        float hv = h[(size_t)node * 64 + k];
        sh32[i][k] = hv;
        sh16[idx] = (f16)hv;
        float mv = fmaxf(agg[(size_t)node * 64 + k] * dinv[node] + convb[k], 0.f);
        sm[idx] = (f16)mv;
    }
    __syncthreads();
    int i = t >> 5, lane = t & 31;
    const f16* mr = sm + i * 64;
    const f16* hr = sh16 + i * 64;
#pragma unroll
    for (int gg = 0; gg < 6; gg++) {
        int j = gg * 32 + lane;
        float gi_ = bih[j], gh_ = bhh[j];
        const f16* wr = sWih + j * WP;
        const f16* wr2 = sWhh + j * WP;
#pragma unroll
        for (int k8 = 0; k8 < 8; k8++) {
            f16x8 wv = *(const f16x8*)(wr + k8 * 8);
            f16x8 mv = *(const f16x8*)(mr + k8 * 8);
            f16x8 wv2 = *(const f16x8*)(wr2 + k8 * 8);
            f16x8 hv = *(const f16x8*)(hr + k8 * 8);
#pragma unroll
            for (int q = 0; q < 8; q++) {
                gi_ += (float)mv[q] * (float)wv[q];
                gh_ += (float)hv[q] * (float)wv2[q];
            }
        }
        sgi[i * 192 + j] = gi_;
        sgh[i * 192 + j] = gh_;
    }
    __syncthreads();
#pragma unroll
    for (int ii = 0; ii < 2; ii++) {
        int idx = t + 256 * ii;
        int i2 = idx >> 6, k = idx & 63;
        int node = nb + i2;
        float r = sigmoidf_(sgi[i2 * 192 + k] + sgh[i2 * 192 + k]);
        float z = sigmoidf_(sgi[i2 * 192 + 64 + k] + sgh[i2 * 192 + 64 + k]);
        float nn = tanhf(sgi[i2 * 192 + 128 + k] + r * sgh[i2 * 192 + 128 + k]);
        h[(size_t)node * 64 + k] = (1.f - z) * nn + z * sh32[i2][k];
    }
}

// ---------------- K8: LSTM step (B=500 blocks), transposed weights ----------------
__global__ void k_lstm(const float* __restrict__ qstar, const float* __restrict__ wihT,
                       const float* __restrict__ whhT, const float* __restrict__ bih,
                       const float* __restrict__ bhh, float* __restrict__ hhv,
                       float* __restrict__ ccv) {
    __shared__ float sq[128], sh[64], sg[256];
    int b = blockIdx.x, t = threadIdx.x;
    if (t < 128) sq[t] = qstar[b * 128 + t];
    if (t >= 128 && t < 192) sh[t - 128] = hhv[b * 64 + t - 128];
    __syncthreads();
    float g = bih[t] + bhh[t];
#pragma unroll 8
    for (int i = 0; i < 128; i++) g += sq[i] * wihT[i * 256 + t];
#pragma unroll 8
    for (int i = 0; i < 64; i++) g += sh[i] * whhT[i * 256 + t];
    sg[t] = g;
    __syncthreads();
    if (t < 64) {
        float ig = sigmoidf_(sg[t]);
        float fg = sigmoidf_(sg[64 + t]);
        float gg = tanhf(sg[128 + t]);
        float og = sigmoidf_(sg[192 + t]);
        float c = fg * ccv[b * 64 + t] + ig * gg;
        ccv[b * 64 + t] = c;
        hhv[b * 64 + t] = og * tanhf(c);
    }
}

// ---------------- K9: Set2Set attention (block per graph) ----------------
#define FP 68
__global__ __launch_bounds__(256) void k_attn(const float* __restrict__ feat,
                                              const float* __restrict__ hhv,
                                              float* __restrict__ qstar) {
    __shared__ float sf[NPG * FP];
    __shared__ float sq[64];
    __shared__ float se[NPG];
    __shared__ float red[2];
    int g = blockIdx.x, t = threadIdx.x;
    if (t < 64) sq[t] = hhv[g * 64 + t];
    const float* fb = feat + (size_t)g * NPG * 64;
    for (int idx = t; idx < NPG * 64; idx += 256)
        sf[(idx >> 6) * FP + (idx & 63)] = fb[idx];
    __syncthreads();
    if (t < NPG) {
        float e = 0.f;
#pragma unroll 8
        for (int o = 0; o < 64; o++) e += sf[t * FP + o] * sq[o];
        se[t] = e;
    }
    __syncthreads();
    if (t < 64) {
        float m = -1e30f;
        for (int i2 = t; i2 < NPG; i2 += 64) m = fmaxf(m, se[i2]);
        for (int d = 32; d; d >>= 1) m = fmaxf(m, __shfl_down(m, d));
        if (t == 0) red[0] = m;
    }
    __syncthreads();
    float emax = red[0];
    if (t < NPG) se[t] = __expf(se[t] - emax);
    __syncthreads();
    if (t < 64) {
        float s = 0.f;
        for (int i2 = t; i2 < NPG; i2 += 64) s += se[i2];
        for (int d = 32; d; d >>= 1) s += __shfl_down(s, d);
        if (t == 0) red[1] = s;
    }
    __syncthreads();
    float dnv = 1.f / red[1];
    if (t < 64) {
        float r = 0.f;
#pragma unroll 4
        for (int n = 0; n < NPG; n++) r += se[n] * sf[n * FP + t];
        qstar[g * 128 + t] = sq[t];
        qstar[g * 128 + 64 + t] = r * dnv;
    }
}

// ---------------- K10: final MLP: relu(qstar@fc1+b1)@fc2+b2 ----------------
__global__ void k_mlp(const float* __restrict__ qstar, const float* __restrict__ w1,
                      const float* __restrict__ b1, const float* __restrict__ w2,
                      const float* __restrict__ b2, float* __restrict__ out) {
    __shared__ float sq[128];
    int b = blockIdx.x, t = threadIdx.x;  // 64 threads
    sq[t] = qstar[b * 128 + t];
    sq[64 + t] = qstar[b * 128 + 64 + t];
    __syncthreads();
    float hsum = b1[t];
#pragma unroll 8
    for (int i = 0; i < 128; i++) hsum += sq[i] * w1[i * 64 + t];
    float p = fmaxf(hsum, 0.f) * w2[t];
    for (int d = 32; d; d >>= 1) p += __shfl_down(p, d);
    if (t == 0) out[b] = p + b2[0];
}

extern "C" void kernel_launch(void* const* d_in, const int* in_sizes, int n_in,
                              void* d_out, int out_size, void* d_ws, size_t ws_size,
                              hipStream_t stream) {
    const float* nfeat = (const float*)d_in[0];
    const float* efeat = (const float*)d_in[1];
    const float* lin0_w = (const float*)d_in[2];
    const float* lin0_b = (const float*)d_in[3];
    const float* ew1 = (const float*)d_in[4];
    const float* eb1 = (const float*)d_in[5];
    const float* ew2 = (const float*)d_in[6];
    const float* eb2 = (const float*)d_in[7];
    const float* convb = (const float*)d_in[8];
    const float* gwih = (const float*)d_in[9];
    const float* gwhh = (const float*)d_in[10];
    const float* gbih = (const float*)d_in[11];
    const float* gbhh = (const float*)d_in[12];
    const float* lwih = (const float*)d_in[13];
    const float* lwhh = (const float*)d_in[14];
    const float* lbih = (const float*)d_in[15];
    const float* lbhh = (const float*)d_in[16];
    const float* fc1w = (const float*)d_in[17];
    const float* fc1b = (const float*)d_in[18];
    const float* fc2w = (const float*)d_in[19];
    const float* fc2b = (const float*)d_in[20];
    const int* src = (const int*)d_in[21];
    const int* dst = (const int*)d_in[22];
    float* out = (float*)d_out;

    char* p = (char*)d_ws;
    auto alloc = [&](size_t bytes) {
        char* q = p;
        p += (bytes + 255) & ~(size_t)255;
        return q;
    };
    f16* u = (f16*)alloc((size_t)EPAD * 136 * 2);           // 27.3 MB
    f16* w2hp = (f16*)alloc((size_t)540672 * 2);            // 1.08 MB
    float* h = (float*)alloc((size_t)NNODE * 64 * 4);       // 12.8 MB
    float* agg = (float*)alloc((size_t)NNODE * 64 * 4);     // 12.8 MB
    int* cnt = (int*)alloc((size_t)NNODE * 4);
    float* dinv = (float*)alloc((size_t)NNODE * 4);
    float* qstar = (float*)alloc((size_t)NGR * 128 * 4);
    float* hh = (float*)alloc((size_t)NGR * 64 * 4);
    float* cc = (float*)alloc((size_t)NGR * 64 * 4);
    float* lwihT = (float*)alloc((size_t)128 * 256 * 4);
    float* lwhhT = (float*)alloc((size_t)64 * 256 * 4);
    f16* gwih16 = (f16*)alloc((size_t)12288 * 2);
    f16* gwhh16 = (f16*)alloc((size_t)12288 * 2);
    if ((size_t)(p - (char*)d_ws) > ws_size) return;  // ~55.5 MB total

    hipMemsetAsync(cnt, 0, (size_t)NNODE * 4, stream);
    hipMemsetAsync(qstar, 0, (size_t)NGR * 128 * 4, stream);
    hipMemsetAsync(hh, 0, (size_t)NGR * 64 * 4, stream);
    hipMemsetAsync(cc, 0, (size_t)NGR * 64 * 4, stream);

    k_node_init<<<(NNODE * 64) / 256, 256, 0, stream>>>(nfeat, lin0_w, lin0_b, h);
    k_edge_mlp<<<(EPAD * 136) / 256, 256, 0, stream>>>(efeat, ew1, eb1, u);
    k_pack_b<<<(540672 + 255) / 256, 256, 0, stream>>>(ew2, eb2, w2hp);
    k_prep_gru<<<48, 256, 0, stream>>>(gwih, gwhh, gwih16, gwhh16);
    k_transpose_f32<<<(256 * 128 + 255) / 256, 256, 0, stream>>>(lwih, lwihT, 256, 128);
    k_transpose_f32<<<(256 * 64 + 255) / 256, 256, 0, stream>>>(lwhh, lwhhT, 256, 64);
    k_deg_count<<<(NEDGE + 255) / 256, 256, 0, stream>>>(dst, cnt);
    k_deg_inv<<<(NNODE + 255) / 256, 256, 0, stream>>>(cnt, dinv);

    for (int it = 0; it < 3; it++) {
        hipMemsetAsync(agg, 0, (size_t)NNODE * 64 * 4, stream);
        k_msg_fused<<<EPAD / 256, 256, 0, stream>>>(h, u, w2hp, src, dst, agg);
        k_gru<<<NNODE / 8, 256, 0, stream>>>(agg, dinv, convb, gwih16, gwhh16, gbih, gbhh, h);
    }
    for (int it = 0; it < 3; it++) {
        k_lstm<<<NGR, 256, 0, stream>>>(qstar, lwihT, lwhhT, lbih, lbhh, hh, cc);
        k_attn<<<NGR, 256, 0, stream>>>(h, hh, qstar);
    }
    k_mlp<<<NGR, 64, 0, stream>>>(qstar, fc1w, fc1b, fc2w, fc2b, out);
}

// Round 3
// 664.792 us; speedup vs baseline: 1.0459x; 1.0459x over previous
//
#include <hip/hip_runtime.h>

#define HD 64
#define NNODE 50000
#define NEDGE 100000
#define NGR 500
#define NPG 100      // nodes per graph (sorted, contiguous, equal size)
#define EPAD 100352  // 392 blocks * 256 edges
#define NCH 66       // K chunks of 128 (K_total = 8448 = 132 ku * 64)
#define KSPLIT 2
#define NC_BLK 33    // chunks per K-split block

typedef _Float16 f16;
typedef _Float16 f16x2 __attribute__((ext_vector_type(2)));
typedef _Float16 f16x8 __attribute__((ext_vector_type(8)));
typedef float f32x4 __attribute__((ext_vector_type(4)));

__device__ __forceinline__ float sigmoidf_(float x) { return 1.f / (1.f + __expf(-x)); }

__device__ __forceinline__ void gload16(const void* g, void* l) {
    __builtin_amdgcn_global_load_lds((const __attribute__((address_space(1))) unsigned int*)g,
                                     (__attribute__((address_space(3))) unsigned int*)l, 16, 0, 0);
}

// ---------------- K1: h = relu(nfeat @ lin0_w + b), [N,32]@[32,64] ----------------
__global__ void k_node_init(const float* __restrict__ nfeat, const float* __restrict__ w,
                            const float* __restrict__ b, float* __restrict__ h) {
    int idx = blockIdx.x * 256 + threadIdx.x;
    int n = idx >> 6, o = idx & 63;
    if (n >= NNODE) return;
    const float* nf = nfeat + n * 32;
    float acc = b[o];
#pragma unroll
    for (int i = 0; i < 32; i++) acc += nf[i] * w[i * 64 + o];
    h[idx] = fmaxf(acc, 0.f);
}

// ---------------- K2: uP[c][e] = (u[e][2c], u[e][2c+1]); u = relu(efeat@ew1+eb1), col128=1 ----
__global__ __launch_bounds__(256) void k_edge_mlp(const float* __restrict__ efeat,
                                                  const float* __restrict__ w,
                                                  const float* __restrict__ b,
                                                  f16x2* __restrict__ uP) {
    __shared__ float sef[256 * 5];
    __shared__ float sw[5 * 128];
    __shared__ float sb[128];
    int t = threadIdx.x;
    int e0 = blockIdx.x * 256;
    for (int idx = t; idx < 1280; idx += 256) {
        int gi = e0 * 5 + idx;
        sef[idx] = (gi < NEDGE * 5) ? efeat[gi] : 0.f;
    }
    for (int idx = t; idx < 640; idx += 256) sw[idx] = w[idx];
    if (t < 128) sb[t] = b[t];
    __syncthreads();
    int e = e0 + t;
    bool valid = e < NEDGE;
    float ef[5];
#pragma unroll
    for (int i = 0; i < 5; i++) ef[i] = sef[t * 5 + i];
#pragma unroll 2
    for (int c = 0; c < NCH; c++) {
        float v[2];
#pragma unroll
        for (int s = 0; s < 2; s++) {
            int kk = 2 * c + s;
            float acc = 0.f;
            if (kk < 128) {
                acc = sb[kk];
#pragma unroll
                for (int i = 0; i < 5; i++) acc += ef[i] * sw[i * 128 + kk];
                acc = fmaxf(acc, 0.f);
            } else if (kk == 128) {
                acc = 1.f;
            }
            v[s] = valid ? acc : 0.f;
        }
        f16x2 pv;
        pv[0] = (f16)v[0];
        pv[1] = (f16)v[1];
        uP[(size_t)c * EPAD + e] = pv;
    }
}

// ---------------- K3: pack W2ext (= [ew2; eb2; zeros], [8448][64]) into MFMA B-fragment order
// w2hp flat f16x8 index F = s*256 + jj*64 + lane; value[q] = W2ext[s*32+(lane>>4)*8+q][jj*16+(lane&15)]
__global__ void k_pack_b(const float* __restrict__ ew2, const float* __restrict__ eb2,
                         f16* __restrict__ w2hp) {
    int idx = blockIdx.x * 256 + threadIdx.x;
    if (idx >= 540672) return;  // 264 slices * 2048 f16
    int q = idx & 7, l = (idx >> 3) & 63, j = (idx >> 9) & 3, s = idx >> 11;
    int k = s * 32 + (l >> 4) * 8 + q;
    int n = j * 16 + (l & 15);
    float v = 0.f;
    if (k < 8192) v = ew2[k * 64 + n];
    else if (k < 8256) v = eb2[(k - 8192) * 64 + n];
    w2hp[idx] = (f16)v;
}

// ---------------- K3b: GRU weights -> f16, gate-col permuted, [192][64] ----------------
// stored row c' = w*48 + t*16 + cc  <->  orig gate row t*64 + w*16 + cc
__global__ void k_prep_gru2(const float* __restrict__ wih, const float* __restrict__ whh,
                            f16* __restrict__ B1, f16* __restrict__ B2) {
    int idx = blockIdx.x * 256 + threadIdx.x;
    if (idx >= 12288) return;
    int cp = idx >> 6, k = idx & 63;
    int w = cp / 48, rem = cp % 48;
    int tg = rem >> 4, cc = rem & 15;
    int orow = tg * 64 + w * 16 + cc;
    B1[idx] = (f16)wih[orow * 64 + k];
    B2[idx] = (f16)whh[orow * 64 + k];
}

// ---------------- K3c: generic small f32 transpose (LSTM weights) ----------------
__global__ void k_transpose_f32(const float* __restrict__ in, float* __restrict__ outp,
                                int rows, int cols) {
    int idx = blockIdx.x * 256 + threadIdx.x;
    if (idx >= rows * cols) return;
    int r = idx / cols, c = idx - r * cols;
    outp[c * rows + r] = in[idx];
}

// ---------------- degree ----------------
__global__ void k_deg_count(const int* __restrict__ dst, int* __restrict__ cnt) {
    int e = blockIdx.x * 256 + threadIdx.x;
    if (e < NEDGE) atomicAdd(&cnt[dst[e]], 1);
}
__global__ void k_deg_inv(const int* __restrict__ cnt, float* __restrict__ dinv) {
    int n = blockIdx.x * 256 + threadIdx.x;
    if (n < NNODE) dinv[n] = 1.f / (float)max(cnt[n], 1);
}

// ---------------- K6: fused msg + scatter, i_rep=8, j_rep=2, K-split, gload_lds dbuf ----------
// Wave w: rows (w>>1)*128 + i*16+lr (i<8), cols (w&1)*32 + j*16+lr (j<2). Block = 256 edges.
__global__ __launch_bounds__(256) void k_msg_fused(
    const float* __restrict__ h, const f16x2* __restrict__ uP, const f16* __restrict__ w2hp,
    const int* __restrict__ src, const int* __restrict__ dst, float* __restrict__ agg) {
    __shared__ __attribute__((aligned(16))) f16 sB[2 * 8192];  // 2 bufs x 1024 f16x8 = 32KB
    __shared__ int ssrc[256], sdst[256];
    int t = threadIdx.x;
    int m0 = blockIdx.x * 256;
    int c0 = blockIdx.y * NC_BLK;
    {
        int e = m0 + t;
        ssrc[t] = (e < NEDGE) ? src[e] : 0;
        sdst[t] = (e < NEDGE) ? dst[e] : -1;
    }
    __syncthreads();
    int w = t >> 6, l = t & 63, lr = l & 15, lg = l >> 4;
    int g = w >> 1, ch = w & 1;
    f16x8 xf[8][2];
#pragma unroll
    for (int i = 0; i < 8; i++) {
        int lrow = g * 128 + i * 16 + lr;
        const float* xb = h + (size_t)ssrc[lrow] * 64;
#pragma unroll
        for (int p = 0; p < 2; p++) {
            float4 v0 = *(const float4*)(xb + p * 32 + lg * 8);
            float4 v1 = *(const float4*)(xb + p * 32 + lg * 8 + 4);
            f16x8 xv;
            xv[0] = (f16)v0.x; xv[1] = (f16)v0.y; xv[2] = (f16)v0.z; xv[3] = (f16)v0.w;
            xv[4] = (f16)v1.x; xv[5] = (f16)v1.y; xv[6] = (f16)v1.z; xv[7] = (f16)v1.w;
            xf[i][p] = xv;
        }
    }
    const f16x8* gB = (const f16x8*)w2hp;
    f16x8* sB8 = (f16x8*)sB;
    {   // stage chunk 0 into buf 0
        const f16x8* gs = gB + (size_t)c0 * 1024 + t;
        f16x8* ld = sB8 + t;
#pragma unroll
        for (int ph = 0; ph < 4; ph++) gload16(gs + ph * 256, ld + ph * 256);
    }
    f16x2 ucur[8], unext[8];
#pragma unroll
    for (int i = 0; i < 8; i++)
        ucur[i] = uP[(size_t)c0 * EPAD + m0 + g * 128 + i * 16 + lr];
    f32x4 acc[8][2];
#pragma unroll
    for (int i = 0; i < 8; i++) {
        acc[i][0] = (f32x4){0.f, 0.f, 0.f, 0.f};
        acc[i][1] = (f32x4){0.f, 0.f, 0.f, 0.f};
    }
    __syncthreads();  // drains vmcnt -> buf0 ready
    for (int c = 0; c < NC_BLK; c++) {
        int buf = c & 1;
        if (c + 1 < NC_BLK) {  // issue next chunk (async) + next u
            const f16x8* gs = gB + (size_t)(c0 + c + 1) * 1024 + t;
            f16x8* ld = sB8 + (buf ^ 1) * 1024 + t;
#pragma unroll
            for (int ph = 0; ph < 4; ph++) gload16(gs + ph * 256, ld + ph * 256);
#pragma unroll
            for (int i = 0; i < 8; i++)
                unext[i] = uP[(size_t)(c0 + c + 1) * EPAD + m0 + g * 128 + i * 16 + lr];
        }
        const f16x8* bb = sB8 + buf * 1024;
#pragma unroll
        for (int sl = 0; sl < 4; sl++) {
            f16x8 b0 = bb[(sl * 4 + ch * 2) * 64 + l];
            f16x8 b1 = bb[(sl * 4 + ch * 2 + 1) * 64 + l];
#pragma unroll
            for (int i = 0; i < 8; i++) {
                f16x8 av = xf[i][sl & 1] * ucur[i][sl >> 1];
                acc[i][0] = __builtin_amdgcn_mfma_f32_16x16x32_f16(av, b0, acc[i][0], 0, 0, 0);
                acc[i][1] = __builtin_amdgcn_mfma_f32_16x16x32_f16(av, b1, acc[i][1], 0, 0, 0);
            }
        }
        if (c + 1 < NC_BLK) {
#pragma unroll
            for (int i = 0; i < 8; i++) ucur[i] = unext[i];
        }
        __syncthreads();  // drains vmcnt: next chunk landed; all reads of cur done
    }
    // scatter: C layout col=lane&15, row=(lane>>4)*4+reg
#pragma unroll
    for (int i = 0; i < 8; i++) {
#pragma unroll
        for (int r = 0; r < 4; r++) {
            int lrow = g * 128 + i * 16 + lg * 4 + r;
            int d = sdst[lrow];
            if (d >= 0) {
                float* ap = agg + (size_t)d * 64 + ch * 32 + lr;
                atomicAdd(ap, acc[i][0][r]);
                atomicAdd(ap + 16, acc[i][1][r]);
            }
        }
    }
}

// ---------------- K7: GRU via MFMA, 64 nodes/block ----------------
#define GWP 72
__global__ __launch_bounds__(256) void k_gru2(const float* __restrict__ agg,
                                              const float* __restrict__ dinv,
                                              const float* __restrict__ convb,
                                              const f16* __restrict__ B1g,
                                              const f16* __restrict__ B2g,
                                              const float* __restrict__ bih,
                                              const float* __restrict__ bhh,
                                              float* __restrict__ h) {
    __shared__ f16 sB1[192 * GWP];
    __shared__ f16 sB2[192 * GWP];
    __shared__ f16 sM[64 * GWP];
    __shared__ f16 sH[64 * GWP];
    int t = threadIdx.x;
    int nb = blockIdx.x * 64;
    const f16x8* g1 = (const f16x8*)B1g;
    const f16x8* g2 = (const f16x8*)B2g;
#pragma unroll
    for (int it = 0; it < 6; it++) {
        int idx = t + 256 * it;
        int c = idx >> 3, k8 = idx & 7;
        *(f16x8*)(sB1 + c * GWP + k8 * 8) = g1[idx];
        *(f16x8*)(sB2 + c * GWP + k8 * 8) = g2[idx];
    }
#pragma unroll
    for (int it = 0; it < 16; it++) {
        int idx = t + 256 * it;
        int node = idx >> 6, k = idx & 63;
        int gn = nb + node;
        float mv = 0.f, hv = 0.f;
        if (gn < NNODE) {
            mv = fmaxf(agg[(size_t)gn * 64 + k] * dinv[gn] + convb[k], 0.f);
            hv = h[(size_t)gn * 64 + k];
        }
        sM[node * GWP + k] = (f16)mv;
        sH[node * GWP + k] = (f16)hv;
    }
    __syncthreads();
    int w = t >> 6, l = t & 63, lr = l & 15, lg = l >> 4;
    f32x4 aih[4][3], ahh[4][3];
#pragma unroll
    for (int i = 0; i < 4; i++)
#pragma unroll
        for (int j = 0; j < 3; j++) {
            aih[i][j] = (f32x4){0.f, 0.f, 0.f, 0.f};
            ahh[i][j] = (f32x4){0.f, 0.f, 0.f, 0.f};
        }
#pragma unroll
    for (int kk = 0; kk < 2; kk++) {
        f16x8 am[4], ah[4], b1[3], b2[3];
#pragma unroll
        for (int i = 0; i < 4; i++) {
            am[i] = *(const f16x8*)(sM + (i * 16 + lr) * GWP + kk * 32 + lg * 8);
            ah[i] = *(const f16x8*)(sH + (i * 16 + lr) * GWP + kk * 32 + lg * 8);
        }
#pragma unroll
        for (int j = 0; j < 3; j++) {
            b1[j] = *(const f16x8*)(sB1 + (w * 48 + j * 16 + lr) * GWP + kk * 32 + lg * 8);
            b2[j] = *(const f16x8*)(sB2 + (w * 48 + j * 16 + lr) * GWP + kk * 32 + lg * 8);
        }
#pragma unroll
        for (int i = 0; i < 4; i++)
#pragma unroll
            for (int j = 0; j < 3; j++) {
                aih[i][j] = __builtin_amdgcn_mfma_f32_16x16x32_f16(am[i], b1[j], aih[i][j], 0, 0, 0);
                ahh[i][j] = __builtin_amdgcn_mfma_f32_16x16x32_f16(ah[i], b2[j], ahh[i][j], 0, 0, 0);
            }
    }
    float bi0 = bih[0 * 64 + w * 16 + lr], bh0 = bhh[0 * 64 + w * 16 + lr];
    float bi1 = bih[1 * 64 + w * 16 + lr], bh1 = bhh[1 * 64 + w * 16 + lr];
    float bi2 = bih[2 * 64 + w * 16 + lr], bh2 = bhh[2 * 64 + w * 16 + lr];
#pragma unroll
    for (int i = 0; i < 4; i++)
#pragma unroll
        for (int r = 0; r < 4; r++) {
            int node = i * 16 + lg * 4 + r;
            int gn = nb + node;
            if (gn >= NNODE) continue;
            float rg = sigmoidf_(aih[i][0][r] + bi0 + ahh[i][0][r] + bh0);
            float z = sigmoidf_(aih[i][1][r] + bi1 + ahh[i][1][r] + bh1);
            float nn = tanhf(aih[i][2][r] + bi2 + rg * (ahh[i][2][r] + bh2));
            size_t off = (size_t)gn * 64 + w * 16 + lr;
            float hold = h[off];
            h[off] = (1.f - z) * nn + z * hold;
        }
}

// ---------------- K8: LSTM step (B=500 blocks), transposed weights ----------------
__global__ void k_lstm(const float* __restrict__ qstar, const float* __restrict__ wihT,
                       const float* __restrict__ whhT, const float* __restrict__ bih,
                       const float* __restrict__ bhh, float* __restrict__ hhv,
                       float* __restrict__ ccv) {
    __shared__ float sq[128], sh[64], sg[256];
    int b = blockIdx.x, t = threadIdx.x;
    if (t < 128) sq[t] = qstar[b * 128 + t];
    if (t >= 128 && t < 192) sh[t - 128] = hhv[b * 64 + t - 128];
    __syncthreads();
    float g = bih[t] + bhh[t];
#pragma unroll 8
    for (int i = 0; i < 128; i++) g += sq[i] * wihT[i * 256 + t];
#pragma unroll 8
    for (int i = 0; i < 64; i++) g += sh[i] * whhT[i * 256 + t];
    sg[t] = g;
    __syncthreads();
    if (t < 64) {
        float ig = sigmoidf_(sg[t]);
        float fg = sigmoidf_(sg[64 + t]);
        float gg = tanhf(sg[128 + t]);
        float og = sigmoidf_(sg[192 + t]);
        float c = fg * ccv[b * 64 + t] + ig * gg;
        ccv[b * 64 + t] = c;
        hhv[b * 64 + t] = og * tanhf(c);
    }
}

// ---------------- K9: Set2Set attention (block per graph) ----------------
#define FP 68
__global__ __launch_bounds__(256) void k_attn(const float* __restrict__ feat,
                                              const float* __restrict__ hhv,
                                              float* __restrict__ qstar) {
    __shared__ float sf[NPG * FP];
    __shared__ float sq[64];
    __shared__ float se[NPG];
    __shared__ float red[2];
    int g = blockIdx.x, t = threadIdx.x;
    if (t < 64) sq[t] = hhv[g * 64 + t];
    const float* fb = feat + (size_t)g * NPG * 64;
    for (int idx = t; idx < NPG * 64; idx += 256)
        sf[(idx >> 6) * FP + (idx & 63)] = fb[idx];
    __syncthreads();
    if (t < NPG) {
        float e = 0.f;
#pragma unroll 8
        for (int o = 0; o < 64; o++) e += sf[t * FP + o] * sq[o];
        se[t] = e;
    }
    __syncthreads();
    if (t < 64) {
        float m = -1e30f;
        for (int i2 = t; i2 < NPG; i2 += 64) m = fmaxf(m, se[i2]);
        for (int d = 32; d; d >>= 1) m = fmaxf(m, __shfl_down(m, d));
        if (t == 0) red[0] = m;
    }
    __syncthreads();
    float emax = red[0];
    if (t < NPG) se[t] = __expf(se[t] - emax);
    __syncthreads();
    if (t < 64) {
        float s = 0.f;
        for (int i2 = t; i2 < NPG; i2 += 64) s += se[i2];
        for (int d = 32; d; d >>= 1) s += __shfl_down(s, d);
        if (t == 0) red[1] = s;
    }
    __syncthreads();
    float dnv = 1.f / red[1];
    if (t < 64) {
        float r = 0.f;
#pragma unroll 4
        for (int n = 0; n < NPG; n++) r += se[n] * sf[n * FP + t];
        qstar[g * 128 + t] = sq[t];
        qstar[g * 128 + 64 + t] = r * dnv;
    }
}

// ---------------- K10: final MLP ----------------
__global__ void k_mlp(const float* __restrict__ qstar, const float* __restrict__ w1,
                      const float* __restrict__ b1, const float* __restrict__ w2,
                      const float* __restrict__ b2, float* __restrict__ out) {
    __shared__ float sq[128];
    int b = blockIdx.x, t = threadIdx.x;  // 64 threads
    sq[t] = qstar[b * 128 + t];
    sq[64 + t] = qstar[b * 128 + 64 + t];
    __syncthreads();
    float hsum = b1[t];
#pragma unroll 8
    for (int i = 0; i < 128; i++) hsum += sq[i] * w1[i * 64 + t];
    float p = fmaxf(hsum, 0.f) * w2[t];
    for (int d = 32; d; d >>= 1) p += __shfl_down(p, d);
    if (t == 0) out[b] = p + b2[0];
}

extern "C" void kernel_launch(void* const* d_in, const int* in_sizes, int n_in,
                              void* d_out, int out_size, void* d_ws, size_t ws_size,
                              hipStream_t stream) {
    const float* nfeat = (const float*)d_in[0];
    const float* efeat = (const float*)d_in[1];
    const float* lin0_w = (const float*)d_in[2];
    const float* lin0_b = (const float*)d_in[3];
    const float* ew1 = (const float*)d_in[4];
    const float* eb1 = (const float*)d_in[5];
    const float* ew2 = (const float*)d_in[6];
    const float* eb2 = (const float*)d_in[7];
    const float* convb = (const float*)d_in[8];
    const float* gwih = (const float*)d_in[9];
    const float* gwhh = (const float*)d_in[10];
    const float* gbih = (const float*)d_in[11];
    const float* gbhh = (const float*)d_in[12];
    const float* lwih = (const float*)d_in[13];
    const float* lwhh = (const float*)d_in[14];
    const float* lbih = (const float*)d_in[15];
    const float* lbhh = (const float*)d_in[16];
    const float* fc1w = (const float*)d_in[17];
    const float* fc1b = (const float*)d_in[18];
    const float* fc2w = (const float*)d_in[19];
    const float* fc2b = (const float*)d_in[20];
    const int* src = (const int*)d_in[21];
    const int* dst = (const int*)d_in[22];
    float* out = (float*)d_out;

    char* p = (char*)d_ws;
    auto alloc = [&](size_t bytes) {
        char* q = p;
        p += (bytes + 255) & ~(size_t)255;
        return q;
    };
    f16x2* uP = (f16x2*)alloc((size_t)NCH * EPAD * 4);      // 26.5 MB
    f16* w2hp = (f16*)alloc((size_t)540672 * 2);            // 1.08 MB
    float* h = (float*)alloc((size_t)NNODE * 64 * 4);       // 12.8 MB
    float* agg = (float*)alloc((size_t)NNODE * 64 * 4);     // 12.8 MB
    int* cnt = (int*)alloc((size_t)NNODE * 4);
    float* dinv = (float*)alloc((size_t)NNODE * 4);
    float* qstar = (float*)alloc((size_t)NGR * 128 * 4);
    float* hh = (float*)alloc((size_t)NGR * 64 * 4);
    float* cc = (float*)alloc((size_t)NGR * 64 * 4);
    float* lwihT = (float*)alloc((size_t)128 * 256 * 4);
    float* lwhhT = (float*)alloc((size_t)64 * 256 * 4);
    f16* gB1 = (f16*)alloc((size_t)12288 * 2);
    f16* gB2 = (f16*)alloc((size_t)12288 * 2);
    if ((size_t)(p - (char*)d_ws) > ws_size) return;  // ~55 MB total

    hipMemsetAsync(cnt, 0, (size_t)NNODE * 4, stream);
    hipMemsetAsync(qstar, 0, (size_t)NGR * 128 * 4, stream);
    hipMemsetAsync(hh, 0, (size_t)NGR * 64 * 4, stream);
    hipMemsetAsync(cc, 0, (size_t)NGR * 64 * 4, stream);

    k_node_init<<<(NNODE * 64) / 256, 256, 0, stream>>>(nfeat, lin0_w, lin0_b, h);
    k_edge_mlp<<<EPAD / 256, 256, 0, stream>>>(efeat, ew1, eb1, uP);
    k_pack_b<<<(540672 + 255) / 256, 256, 0, stream>>>(ew2, eb2, w2hp);
    k_prep_gru2<<<48, 256, 0, stream>>>(gwih, gwhh, gB1, gB2);
    k_transpose_f32<<<(256 * 128 + 255) / 256, 256, 0, stream>>>(lwih, lwihT, 256, 128);
    k_transpose_f32<<<(256 * 64 + 255) / 256, 256, 0, stream>>>(lwhh, lwhhT, 256, 64);
    k_deg_count<<<(NEDGE + 255) / 256, 256, 0, stream>>>(dst, cnt);
    k_deg_inv<<<(NNODE + 255) / 256, 256, 0, stream>>>(cnt, dinv);

    for (int it = 0; it < 3; it++) {
        hipMemsetAsync(agg, 0, (size_t)NNODE * 64 * 4, stream);
        k_msg_fused<<<dim3(EPAD / 256, KSPLIT), 256, 0, stream>>>(h, uP, w2hp, src, dst, agg);
        k_gru2<<<(NNODE + 63) / 64, 256, 0, stream>>>(agg, dinv, convb, gB1, gB2, gbih, gbhh, h);
    }
    for (int it = 0; it < 3; it++) {
        k_lstm<<<NGR, 256, 0, stream>>>(qstar, lwihT, lwhhT, lbih, lbhh, hh, cc);
        k_attn<<<NGR, 256, 0, stream>>>(h, hh, qstar);
    }
    k_mlp<<<NGR, 64, 0, stream>>>(qstar, fc1w, fc1b, fc2w, fc2b, out);
}

// Round 4
// 535.889 us; speedup vs baseline: 1.2975x; 1.2405x over previous
//
#include <hip/hip_runtime.h>

#define HD 64
#define NNODE 50000
#define NEDGE 100000
#define NGR 500
#define NPG 100      // nodes per graph (sorted, contiguous, equal size)
#define EPAD 100352  // 784 * 128
#define NCH 66       // K chunks of 128 (K_total = 8448 = 132 ku * 64)

typedef _Float16 f16;
typedef _Float16 f16x2 __attribute__((ext_vector_type(2)));
typedef _Float16 f16x8 __attribute__((ext_vector_type(8)));
typedef float f32x4 __attribute__((ext_vector_type(4)));

__device__ __forceinline__ float sigmoidf_(float x) { return 1.f / (1.f + __expf(-x)); }

// ---------------- K1: h = relu(nfeat @ lin0_w + b), [N,32]@[32,64] ----------------
__global__ void k_node_init(const float* __restrict__ nfeat, const float* __restrict__ w,
                            const float* __restrict__ b, float* __restrict__ h) {
    int idx = blockIdx.x * 256 + threadIdx.x;
    int n = idx >> 6, o = idx & 63;
    if (n >= NNODE) return;
    const float* nf = nfeat + n * 32;
    float acc = b[o];
#pragma unroll
    for (int i = 0; i < 32; i++) acc += nf[i] * w[i * 64 + o];
    h[idx] = fmaxf(acc, 0.f);
}

// ---------------- K2: uP[c][e] = (u[e][2c], u[e][2c+1]); u = relu(efeat@ew1+eb1), col128=1 ----
__global__ __launch_bounds__(256) void k_edge_mlp(const float* __restrict__ efeat,
                                                  const float* __restrict__ w,
                                                  const float* __restrict__ b,
                                                  f16x2* __restrict__ uP) {
    __shared__ float sef[256 * 5];
    __shared__ float sw[5 * 128];
    __shared__ float sb[128];
    int t = threadIdx.x;
    int e0 = blockIdx.x * 256;
    for (int idx = t; idx < 1280; idx += 256) {
        int gi = e0 * 5 + idx;
        sef[idx] = (gi < NEDGE * 5) ? efeat[gi] : 0.f;
    }
    for (int idx = t; idx < 640; idx += 256) sw[idx] = w[idx];
    if (t < 128) sb[t] = b[t];
    __syncthreads();
    int e = e0 + t;
    bool valid = e < NEDGE;
    float ef[5];
#pragma unroll
    for (int i = 0; i < 5; i++) ef[i] = sef[t * 5 + i];
#pragma unroll 2
    for (int c = 0; c < NCH; c++) {
        float v[2];
#pragma unroll
        for (int s = 0; s < 2; s++) {
            int kk = 2 * c + s;
            float acc = 0.f;
            if (kk < 128) {
                acc = sb[kk];
#pragma unroll
                for (int i = 0; i < 5; i++) acc += ef[i] * sw[i * 128 + kk];
                acc = fmaxf(acc, 0.f);
            } else if (kk == 128) {
                acc = 1.f;
            }
            v[s] = valid ? acc : 0.f;
        }
        f16x2 pv;
        pv[0] = (f16)v[0];
        pv[1] = (f16)v[1];
        uP[(size_t)c * EPAD + e] = pv;
    }
}

// ---------------- K3: pack W2ext (= [ew2; eb2; zeros], [8448][64]) into MFMA B-fragment order
// w2hp flat f16x8 index F = s*256 + jj*64 + lane; value[q] = W2ext[s*32+(lane>>4)*8+q][jj*16+(lane&15)]
__global__ void k_pack_b(const float* __restrict__ ew2, const float* __restrict__ eb2,
                         f16* __restrict__ w2hp) {
    int idx = blockIdx.x * 256 + threadIdx.x;
    if (idx >= 540672) return;  // 264 slices * 2048 f16
    int q = idx & 7, l = (idx >> 3) & 63, j = (idx >> 9) & 3, s = idx >> 11;
    int k = s * 32 + (l >> 4) * 8 + q;
    int n = j * 16 + (l & 15);
    float v = 0.f;
    if (k < 8192) v = ew2[k * 64 + n];
    else if (k < 8256) v = eb2[(k - 8192) * 64 + n];
    w2hp[idx] = (f16)v;
}

// ---------------- K3b: GRU weights -> f16, gate-col permuted, [192][64] ----------------
__global__ void k_prep_gru2(const float* __restrict__ wih, const float* __restrict__ whh,
                            f16* __restrict__ B1, f16* __restrict__ B2) {
    int idx = blockIdx.x * 256 + threadIdx.x;
    if (idx >= 12288) return;
    int cp = idx >> 6, k = idx & 63;
    int w = cp / 48, rem = cp % 48;
    int tg = rem >> 4, cc = rem & 15;
    int orow = tg * 64 + w * 16 + cc;
    B1[idx] = (f16)wih[orow * 64 + k];
    B2[idx] = (f16)whh[orow * 64 + k];
}

// ---------------- K3c: generic small f32 transpose (LSTM weights) ----------------
__global__ void k_transpose_f32(const float* __restrict__ in, float* __restrict__ outp,
                                int rows, int cols) {
    int idx = blockIdx.x * 256 + threadIdx.x;
    if (idx >= rows * cols) return;
    int r = idx / cols, c = idx - r * cols;
    outp[c * rows + r] = in[idx];
}

// ---------------- padded index arrays ----------------
__global__ void k_pad_idx(const int* __restrict__ src, const int* __restrict__ dst,
                          int* __restrict__ srcP, int* __restrict__ dstP) {
    int e = blockIdx.x * 256 + threadIdx.x;
    if (e >= EPAD) return;
    srcP[e] = (e < NEDGE) ? src[e] : 0;
    dstP[e] = (e < NEDGE) ? dst[e] : -1;
}

// ---------------- degree ----------------
__global__ void k_deg_count(const int* __restrict__ dst, int* __restrict__ cnt) {
    int e = blockIdx.x * 256 + threadIdx.x;
    if (e < NEDGE) atomicAdd(&cnt[dst[e]], 1);
}
__global__ void k_deg_inv(const int* __restrict__ cnt, float* __restrict__ dinv) {
    int n = blockIdx.x * 256 + threadIdx.x;
    if (n < NNODE) dinv[n] = 1.f / (float)max(cnt[n], 1);
}

// ---------------- K6: fused msg + scatter, LDS-free, all-register pipeline ----------------
// One wave per block. Wave = 128 edges x 32 cols (i_rep=8, j_rep=2).
// B fragments stream from L2 (w2hp is 1MB, hot). Register double-buffer over 66 K-chunks.
#define MSG_PHASE(BC, UC, BN, UN, CNEXT, DOPF)                                                        \
    {                                                                                                 \
        if (DOPF) {                                                                                   \
            const f16x8* gsrc = gB + (size_t)(CNEXT) * 1024 + ch * 128 + l;                           \
            _Pragma("unroll") for (int sl = 0; sl < 4; sl++) {                                        \
                BN[sl * 2] = gsrc[sl * 256];                                                          \
                BN[sl * 2 + 1] = gsrc[sl * 256 + 64];                                                 \
            }                                                                                         \
            const f16x2* us = uP + (size_t)(CNEXT) * EPAD + eb + lr;                                  \
            _Pragma("unroll") for (int i = 0; i < 8; i++) UN[i] = us[i * 16];                         \
        }                                                                                             \
        _Pragma("unroll") for (int sl = 0; sl < 4; sl++) {                                            \
            _Pragma("unroll") for (int i = 0; i < 8; i++) {                                           \
                f16x8 av = xf[i][sl & 1] * UC[i][sl >> 1];                                            \
                acc[i][0] = __builtin_amdgcn_mfma_f32_16x16x32_f16(av, BC[sl * 2], acc[i][0], 0, 0, 0);       \
                acc[i][1] = __builtin_amdgcn_mfma_f32_16x16x32_f16(av, BC[sl * 2 + 1], acc[i][1], 0, 0, 0);   \
            }                                                                                         \
        }                                                                                             \
    }

__global__ __launch_bounds__(64) void k_msg_fused(
    const float* __restrict__ h, const f16x2* __restrict__ uP, const f16* __restrict__ w2hp,
    const int* __restrict__ srcP, const int* __restrict__ dstP, float* __restrict__ agg) {
    int l = threadIdx.x;
    int wid = blockIdx.x;
    int eb = (wid >> 1) * 128;  // edge base
    int ch = wid & 1;           // column half (32 cols)
    int lr = l & 15, lg = l >> 4;
    // A-side x fragments: xf[i][p][q] = f16(h[src[eb+i*16+lr]][p*32 + lg*8 + q])
    f16x8 xf[8][2];
#pragma unroll
    for (int i = 0; i < 8; i++) {
        const float* xb = h + (size_t)srcP[eb + i * 16 + lr] * 64;
#pragma unroll
        for (int p = 0; p < 2; p++) {
            float4 v0 = *(const float4*)(xb + p * 32 + lg * 8);
            float4 v1 = *(const float4*)(xb + p * 32 + lg * 8 + 4);
            f16x8 xv;
            xv[0] = (f16)v0.x; xv[1] = (f16)v0.y; xv[2] = (f16)v0.z; xv[3] = (f16)v0.w;
            xv[4] = (f16)v1.x; xv[5] = (f16)v1.y; xv[6] = (f16)v1.z; xv[7] = (f16)v1.w;
            xf[i][p] = xv;
        }
    }
    const f16x8* gB = (const f16x8*)w2hp;
    f32x4 acc[8][2];
#pragma unroll
    for (int i = 0; i < 8; i++) {
        acc[i][0] = (f32x4){0.f, 0.f, 0.f, 0.f};
        acc[i][1] = (f32x4){0.f, 0.f, 0.f, 0.f};
    }
    f16x8 bA[8], bB[8];
    f16x2 uA[8], uB[8];
    {   // prologue: chunk 0 -> A
        const f16x8* gsrc = gB + ch * 128 + l;
#pragma unroll
        for (int sl = 0; sl < 4; sl++) {
            bA[sl * 2] = gsrc[sl * 256];
            bA[sl * 2 + 1] = gsrc[sl * 256 + 64];
        }
        const f16x2* us = uP + eb + lr;
#pragma unroll
        for (int i = 0; i < 8; i++) uA[i] = us[i * 16];
    }
    for (int c = 0; c < NCH; c += 2) {
        MSG_PHASE(bA, uA, bB, uB, c + 1, true);
        MSG_PHASE(bB, uB, bA, uA, c + 2, (c + 2 < NCH));
    }
    // scatter: C layout col=lane&15, row=(lane>>4)*4+reg
#pragma unroll
    for (int i = 0; i < 8; i++) {
        int rb = eb + i * 16 + lg * 4;
        int4 d4 = *(const int4*)(dstP + rb);
#pragma unroll
        for (int r = 0; r < 4; r++) {
            int d = (r == 0) ? d4.x : (r == 1) ? d4.y : (r == 2) ? d4.z : d4.w;
            if (d >= 0) {
                float* ap = agg + (size_t)d * 64 + ch * 32 + lr;
                atomicAdd(ap, acc[i][0][r]);
                atomicAdd(ap + 16, acc[i][1][r]);
            }
        }
    }
}

// ---------------- K7: GRU via MFMA, 64 nodes/block ----------------
#define GWP 72
__global__ __launch_bounds__(256) void k_gru2(const float* __restrict__ agg,
                                              const float* __restrict__ dinv,
                                              const float* __restrict__ convb,
                                              const f16* __restrict__ B1g,
                                              const f16* __restrict__ B2g,
                                              const float* __restrict__ bih,
                                              const float* __restrict__ bhh,
                                              float* __restrict__ h) {
    __shared__ f16 sB1[192 * GWP];
    __shared__ f16 sB2[192 * GWP];
    __shared__ f16 sM[64 * GWP];
    __shared__ f16 sH[64 * GWP];
    int t = threadIdx.x;
    int nb = blockIdx.x * 64;
    const f16x8* g1 = (const f16x8*)B1g;
    const f16x8* g2 = (const f16x8*)B2g;
#pragma unroll
    for (int it = 0; it < 6; it++) {
        int idx = t + 256 * it;
        int c = idx >> 3, k8 = idx & 7;
        *(f16x8*)(sB1 + c * GWP + k8 * 8) = g1[idx];
        *(f16x8*)(sB2 + c * GWP + k8 * 8) = g2[idx];
    }
#pragma unroll
    for (int it = 0; it < 16; it++) {
        int idx = t + 256 * it;
        int node = idx >> 6, k = idx & 63;
        int gn = nb + node;
        float mv = 0.f, hv = 0.f;
        if (gn < NNODE) {
            mv = fmaxf(agg[(size_t)gn * 64 + k] * dinv[gn] + convb[k], 0.f);
            hv = h[(size_t)gn * 64 + k];
        }
        sM[node * GWP + k] = (f16)mv;
        sH[node * GWP + k] = (f16)hv;
    }
    __syncthreads();
    int w = t >> 6, l = t & 63, lr = l & 15, lg = l >> 4;
    f32x4 aih[4][3], ahh[4][3];
#pragma unroll
    for (int i = 0; i < 4; i++)
#pragma unroll
        for (int j = 0; j < 3; j++) {
            aih[i][j] = (f32x4){0.f, 0.f, 0.f, 0.f};
            ahh[i][j] = (f32x4){0.f, 0.f, 0.f, 0.f};
        }
#pragma unroll
    for (int kk = 0; kk < 2; kk++) {
        f16x8 am[4], ah[4], b1[3], b2[3];
#pragma unroll
        for (int i = 0; i < 4; i++) {
            am[i] = *(const f16x8*)(sM + (i * 16 + lr) * GWP + kk * 32 + lg * 8);
            ah[i] = *(const f16x8*)(sH + (i * 16 + lr) * GWP + kk * 32 + lg * 8);
        }
#pragma unroll
        for (int j = 0; j < 3; j++) {
            b1[j] = *(const f16x8*)(sB1 + (w * 48 + j * 16 + lr) * GWP + kk * 32 + lg * 8);
            b2[j] = *(const f16x8*)(sB2 + (w * 48 + j * 16 + lr) * GWP + kk * 32 + lg * 8);
        }
#pragma unroll
        for (int i = 0; i < 4; i++)
#pragma unroll
            for (int j = 0; j < 3; j++) {
                aih[i][j] = __builtin_amdgcn_mfma_f32_16x16x32_f16(am[i], b1[j], aih[i][j], 0, 0, 0);
                ahh[i][j] = __builtin_amdgcn_mfma_f32_16x16x32_f16(ah[i], b2[j], ahh[i][j], 0, 0, 0);
            }
    }
    float bi0 = bih[0 * 64 + w * 16 + lr], bh0 = bhh[0 * 64 + w * 16 + lr];
    float bi1 = bih[1 * 64 + w * 16 + lr], bh1 = bhh[1 * 64 + w * 16 + lr];
    float bi2 = bih[2 * 64 + w * 16 + lr], bh2 = bhh[2 * 64 + w * 16 + lr];
#pragma unroll
    for (int i = 0; i < 4; i++)
#pragma unroll
        for (int r = 0; r < 4; r++) {
            int node = i * 16 + lg * 4 + r;
            int gn = nb + node;
            if (gn >= NNODE) continue;
            float rg = sigmoidf_(aih[i][0][r] + bi0 + ahh[i][0][r] + bh0);
            float z = sigmoidf_(aih[i][1][r] + bi1 + ahh[i][1][r] + bh1);
            float nn = tanhf(aih[i][2][r] + bi2 + rg * (ahh[i][2][r] + bh2));
            size_t off = (size_t)gn * 64 + w * 16 + lr;
            float hold = h[off];
            h[off] = (1.f - z) * nn + z * hold;
        }
}

// ---------------- K8: LSTM step (B=500 blocks), transposed weights ----------------
__global__ void k_lstm(const float* __restrict__ qstar, const float* __restrict__ wihT,
                       const float* __restrict__ whhT, const float* __restrict__ bih,
                       const float* __restrict__ bhh, float* __restrict__ hhv,
                       float* __restrict__ ccv) {
    __shared__ float sq[128], sh[64], sg[256];
    int b = blockIdx.x, t = threadIdx.x;
    if (t < 128) sq[t] = qstar[b * 128 + t];
    if (t >= 128 && t < 192) sh[t - 128] = hhv[b * 64 + t - 128];
    __syncthreads();
    float g = bih[t] + bhh[t];
#pragma unroll 8
    for (int i = 0; i < 128; i++) g += sq[i] * wihT[i * 256 + t];
#pragma unroll 8
    for (int i = 0; i < 64; i++) g += sh[i] * whhT[i * 256 + t];
    sg[t] = g;
    __syncthreads();
    if (t < 64) {
        float ig = sigmoidf_(sg[t]);
        float fg = sigmoidf_(sg[64 + t]);
        float gg = tanhf(sg[128 + t]);
        float og = sigmoidf_(sg[192 + t]);
        float c = fg * ccv[b * 64 + t] + ig * gg;
        ccv[b * 64 + t] = c;
        hhv[b * 64 + t] = og * tanhf(c);
    }
}

// ---------------- K9: Set2Set attention (block per graph) ----------------
#define FP 68
__global__ __launch_bounds__(256) void k_attn(const float* __restrict__ feat,
                                              const float* __restrict__ hhv,
                                              float* __restrict__ qstar) {
    __shared__ float sf[NPG * FP];
    __shared__ float sq[64];
    __shared__ float se[NPG];
    __shared__ float red[2];
    int g = blockIdx.x, t = threadIdx.x;
    if (t < 64) sq[t] = hhv[g * 64 + t];
    const float* fb = feat + (size_t)g * NPG * 64;
    for (int idx = t; idx < NPG * 64; idx += 256)
        sf[(idx >> 6) * FP + (idx & 63)] = fb[idx];
    __syncthreads();
    if (t < NPG) {
        float e = 0.f;
#pragma unroll 8
        for (int o = 0; o < 64; o++) e += sf[t * FP + o] * sq[o];
        se[t] = e;
    }
    __syncthreads();
    if (t < 64) {
        float m = -1e30f;
        for (int i2 = t; i2 < NPG; i2 += 64) m = fmaxf(m, se[i2]);
        for (int d = 32; d; d >>= 1) m = fmaxf(m, __shfl_down(m, d));
        if (t == 0) red[0] = m;
    }
    __syncthreads();
    float emax = red[0];
    if (t < NPG) se[t] = __expf(se[t] - emax);
    __syncthreads();
    if (t < 64) {
        float s = 0.f;
        for (int i2 = t; i2 < NPG; i2 += 64) s += se[i2];
        for (int d = 32; d; d >>= 1) s += __shfl_down(s, d);
        if (t == 0) red[1] = s;
    }
    __syncthreads();
    float dnv = 1.f / red[1];
    if (t < 64) {
        float r = 0.f;
#pragma unroll 4
        for (int n = 0; n < NPG; n++) r += se[n] * sf[n * FP + t];
        qstar[g * 128 + t] = sq[t];
        qstar[g * 128 + 64 + t] = r * dnv;
    }
}

// ---------------- K10: final MLP ----------------
__global__ void k_mlp(const float* __restrict__ qstar, const float* __restrict__ w1,
                      const float* __restrict__ b1, const float* __restrict__ w2,
                      const float* __restrict__ b2, float* __restrict__ out) {
    __shared__ float sq[128];
    int b = blockIdx.x, t = threadIdx.x;  // 64 threads
    sq[t] = qstar[b * 128 + t];
    sq[64 + t] = qstar[b * 128 + 64 + t];
    __syncthreads();
    float hsum = b1[t];
#pragma unroll 8
    for (int i = 0; i < 128; i++) hsum += sq[i] * w1[i * 64 + t];
    float p = fmaxf(hsum, 0.f) * w2[t];
    for (int d = 32; d; d >>= 1) p += __shfl_down(p, d);
    if (t == 0) out[b] = p + b2[0];
}

extern "C" void kernel_launch(void* const* d_in, const int* in_sizes, int n_in,
                              void* d_out, int out_size, void* d_ws, size_t ws_size,
                              hipStream_t stream) {
    const float* nfeat = (const float*)d_in[0];
    const float* efeat = (const float*)d_in[1];
    const float* lin0_w = (const float*)d_in[2];
    const float* lin0_b = (const float*)d_in[3];
    const float* ew1 = (const float*)d_in[4];
    const float* eb1 = (const float*)d_in[5];
    const float* ew2 = (const float*)d_in[6];
    const float* eb2 = (const float*)d_in[7];
    const float* convb = (const float*)d_in[8];
    const float* gwih = (const float*)d_in[9];
    const float* gwhh = (const float*)d_in[10];
    const float* gbih = (const float*)d_in[11];
    const float* gbhh = (const float*)d_in[12];
    const float* lwih = (const float*)d_in[13];
    const float* lwhh = (const float*)d_in[14];
    const float* lbih = (const float*)d_in[15];
    const float* lbhh = (const float*)d_in[16];
    const float* fc1w = (const float*)d_in[17];
    const float* fc1b = (const float*)d_in[18];
    const float* fc2w = (const float*)d_in[19];
    const float* fc2b = (const float*)d_in[20];
    const int* src = (const int*)d_in[21];
    const int* dst = (const int*)d_in[22];
    float* out = (float*)d_out;

    char* p = (char*)d_ws;
    auto alloc = [&](size_t bytes) {
        char* q = p;
        p += (bytes + 255) & ~(size_t)255;
        return q;
    };
    f16x2* uP = (f16x2*)alloc((size_t)NCH * EPAD * 4);      // 26.5 MB
    f16* w2hp = (f16*)alloc((size_t)540672 * 2);            // 1.08 MB
    float* h = (float*)alloc((size_t)NNODE * 64 * 4);       // 12.8 MB
    float* agg = (float*)alloc((size_t)NNODE * 64 * 4);     // 12.8 MB
    int* cnt = (int*)alloc((size_t)NNODE * 4);
    float* dinv = (float*)alloc((size_t)NNODE * 4);
    float* qstar = (float*)alloc((size_t)NGR * 128 * 4);
    float* hh = (float*)alloc((size_t)NGR * 64 * 4);
    float* cc = (float*)alloc((size_t)NGR * 64 * 4);
    float* lwihT = (float*)alloc((size_t)128 * 256 * 4);
    float* lwhhT = (float*)alloc((size_t)64 * 256 * 4);
    f16* gB1 = (f16*)alloc((size_t)12288 * 2);
    f16* gB2 = (f16*)alloc((size_t)12288 * 2);
    int* srcP = (int*)alloc((size_t)EPAD * 4);
    int* dstP = (int*)alloc((size_t)EPAD * 4);
    if ((size_t)(p - (char*)d_ws) > ws_size) return;  // ~57 MB total

    hipMemsetAsync(cnt, 0, (size_t)NNODE * 4, stream);
    hipMemsetAsync(qstar, 0, (size_t)NGR * 128 * 4, stream);
    hipMemsetAsync(hh, 0, (size_t)NGR * 64 * 4, stream);
    hipMemsetAsync(cc, 0, (size_t)NGR * 64 * 4, stream);

    k_node_init<<<(NNODE * 64) / 256, 256, 0, stream>>>(nfeat, lin0_w, lin0_b, h);
    k_edge_mlp<<<EPAD / 256, 256, 0, stream>>>(efeat, ew1, eb1, uP);
    k_pack_b<<<(540672 + 255) / 256, 256, 0, stream>>>(ew2, eb2, w2hp);
    k_prep_gru2<<<48, 256, 0, stream>>>(gwih, gwhh, gB1, gB2);
    k_transpose_f32<<<(256 * 128 + 255) / 256, 256, 0, stream>>>(lwih, lwihT, 256, 128);
    k_transpose_f32<<<(256 * 64 + 255) / 256, 256, 0, stream>>>(lwhh, lwhhT, 256, 64);
    k_pad_idx<<<EPAD / 256, 256, 0, stream>>>(src, dst, srcP, dstP);
    k_deg_count<<<(NEDGE + 255) / 256, 256, 0, stream>>>(dst, cnt);
    k_deg_inv<<<(NNODE + 255) / 256, 256, 0, stream>>>(cnt, dinv);

    for (int it = 0; it < 3; it++) {
        hipMemsetAsync(agg, 0, (size_t)NNODE * 64 * 4, stream);
        k_msg_fused<<<(EPAD / 128) * 2, 64, 0, stream>>>(h, uP, w2hp, srcP, dstP, agg);
        k_gru2<<<(NNODE + 63) / 64, 256, 0, stream>>>(agg, dinv, convb, gB1, gB2, gbih, gbhh, h);
    }
    for (int it = 0; it < 3; it++) {
        k_lstm<<<NGR, 256, 0, stream>>>(qstar, lwihT, lwhhT, lbih, lbhh, hh, cc);
        k_attn<<<NGR, 256, 0, stream>>>(h, hh, qstar);
    }
    k_mlp<<<NGR, 64, 0, stream>>>(qstar, fc1w, fc1b, fc2w, fc2b, out);
}